// Round 16
// baseline (199.483 us; speedup 1.0000x reference)
//
#include <hip/hip_runtime.h>
#include <cstdint>
#include <cstddef>

#define H1DIM 512
#define H2DIM 256
#define DNODE 1280
#define NPACK 1024   // GEMM1 packed output width (XWt | XWb), bf16

typedef __attribute__((ext_vector_type(8))) short short8v;
typedef __attribute__((ext_vector_type(4))) float f32x4;
typedef __attribute__((ext_vector_type(4))) unsigned short us4;

__device__ __forceinline__ unsigned short f2bf(float f) {
    unsigned int u = __builtin_bit_cast(unsigned int, f);
    u += 0x7fffu + ((u >> 16) & 1u);   // RNE
    return (unsigned short)(u >> 16);
}
__device__ __forceinline__ float bf2f(unsigned short h) {
    unsigned int u = ((unsigned int)h) << 16;
    return __builtin_bit_cast(float, u);
}

// chunk-major LDS index (2-way/zero bank conflicts, proven R6-R10):
// tile row R, k-chunk q (8 ushorts) -> segment R>>4, slot q*16 + (R&15),
// ushort index = (R>>4)*512 + slot*8. Fragment read: seg*512 + lane*8.
__device__ __forceinline__ int cmi(int R, int kq) {
    return ((R >> 4) << 9) + (((kq >> 3) << 4) + (R & 15)) * 8;
}

// ---------------- fused prep: cvt_x || hist || 3 weight transposes (block-range dispatch) ----
// R12 lesson: block-range fusion only between regions of matching small footprint.
__global__ __launch_bounds__(256) void prep_k(
    const float* __restrict__ x, unsigned short* __restrict__ xb, int ncvt, int ntot,
    const int* __restrict__ e1, int* __restrict__ hist, int nhist, int E,
    const float* __restrict__ W1, unsigned short* __restrict__ Bpt1,
    const float* __restrict__ W2, unsigned short* __restrict__ W2t)
{
    __shared__ float tile[32][33];
    int b = blockIdx.x;

    if (b < ncvt) {                       // region 1: x fp32 -> bf16 (f32x4/thread)
        int i = b * 256 + threadIdx.x;
        if (i * 4 < ntot) {
            f32x4 v = *reinterpret_cast<const f32x4*>(x + (size_t)i * 4);
            us4 o;
            o[0] = f2bf(v.x); o[1] = f2bf(v.y); o[2] = f2bf(v.z); o[3] = f2bf(v.w);
            *reinterpret_cast<us4*>(xb + (size_t)i * 4) = o;
        }
        return;
    }
    b -= ncvt;
    if (b < nhist) {                      // region 2: degree histogram
        int e = b * 256 + threadIdx.x;
        if (e < E) atomicAdd(&hist[e1[e]], 1);
        return;
    }
    b -= nhist;

    // region 3: transpose+cvt (W1 top | W1 bottom | W2), block-uniform branch
    const float* src; unsigned short* dst; int ldsrc, lddst, bx, by;
    if (b < 640) {                        // W1 top: [1280][512] -> Bpt1 [512][1280]
        src = W1; dst = Bpt1; ldsrc = H1DIM; lddst = DNODE; bx = b & 15; by = b >> 4;
    } else if (b < 1280) {                // W1 bottom
        b -= 640;
        src = W1 + (size_t)DNODE * H1DIM; dst = Bpt1 + (size_t)H1DIM * DNODE;
        ldsrc = H1DIM; lddst = DNODE; bx = b & 15; by = b >> 4;
    } else {                              // W2: [512][256] -> W2t [256][512]
        b -= 1280;
        src = W2; dst = W2t; ldsrc = H2DIM; lddst = H1DIM; bx = b & 7; by = b >> 3;
    }
    const int c0 = bx * 32, r0 = by * 32;
    const int tx = threadIdx.x & 31;
    const int ty = threadIdx.x >> 5;
#pragma unroll
    for (int rr = ty; rr < 32; rr += 8)
        tile[rr][tx] = src[(size_t)(r0 + rr) * ldsrc + c0 + tx];
    __syncthreads();
#pragma unroll
    for (int rr = ty; rr < 32; rr += 8)
        dst[(size_t)(c0 + rr) * lddst + r0 + tx] = f2bf(tile[tx][rr]);
}

// ---------------- unified bf16 MFMA GEMM, tile 128x256, BK=32, 512 thr (8 waves 2Mx4N) ----
// R8 schedule: reg-staged loads, double-buffered chunk-major LDS, ONE barrier per K-step.
// MODE 0: blocks [0,nwg) GEMM1 tiles (XCD swizzle); block nwg runs the CSR scan (hidden).
// MODE 1: GEMM2. Epilogue fuses final gumbel-sigmoid for rows >= Nn; kld partial goes to
//   kldp[blockIdx] (NON-atomic; R14 lesson). reduce_k sums partials, plain store, 0 atomics.
template <int MODE>
__global__ __launch_bounds__(512) void gemm_u_k(
    const unsigned short* __restrict__ Ab,
    const unsigned short* __restrict__ Bt,
    unsigned short* __restrict__ Cb,
    const unsigned short* __restrict__ out1b,
    const unsigned short* __restrict__ XWb16,
    const float* __restrict__ b1,
    const float* __restrict__ b2,
    const float* __restrict__ Wl,
    const int* __restrict__ e0, const int* __restrict__ e1,
    int* __restrict__ off, const int* __restrict__ srcs,
    unsigned short* __restrict__ h2b,
    int* __restrict__ hist, int* __restrict__ cursor, float* __restrict__ dinv,
    const float* __restrict__ eps, const float* __restrict__ blp, float* __restrict__ dout,
    float* __restrict__ kldp,
    int M, int K, int Nn, int nwg)
{
    const int tid  = threadIdx.x;

    if (MODE == 0 && blockIdx.x >= (unsigned)nwg) {
        // ---- CSR scan + dinv (512-thread variant), 1 block, hidden under GEMM1 ----
        __shared__ int part[512];
        const int t = tid;
        const int per = (Nn + 511) / 512;
        const int base = t * per;
        int s = 0;
        for (int i = 0; i < per; ++i) { int b = base + i; if (b < Nn) s += hist[b]; }
        part[t] = s;
        __syncthreads();
        for (int d = 1; d < 512; d <<= 1) {
            int v = (t >= d) ? part[t - d] : 0;
            __syncthreads();
            part[t] += v;
            __syncthreads();
        }
        int run = (t == 0) ? 0 : part[t - 1];
        for (int i = 0; i < per; ++i) {
            int b = base + i;
            if (b < Nn) {
                int h = hist[b];
                off[b] = run;
                run += h;
                cursor[b] = 0;
                dinv[b] = rsqrtf(1.0f + (float)h);
            }
        }
        if (t == 511) off[Nn] = run;
        return;
    }

    __shared__ alignas(16) unsigned short As[2][128 * 32];
    __shared__ alignas(16) unsigned short Bs[2][256 * 32];
    __shared__ float b1s[H1DIM];
    __shared__ float b2s[H2DIM];
    __shared__ float wls[H2DIM];
    __shared__ float preacc[128];
    __shared__ float kpart[8];

    const int lane = tid & 63;
    const int w    = tid >> 6;
    const int wm   = w >> 2, wn = w & 3;

    int mb, n0;
    if (MODE == 0) {
        // bijective XCD swizzle (m204): consecutive logical tiles land on one XCD
        const int q = nwg >> 3, r = nwg & 7;
        const int xcd = blockIdx.x & 7;
        const int base = (xcd < r) ? xcd * (q + 1) : r * (q + 1) + (xcd - r) * q;
        const int wg = base + (blockIdx.x >> 3);
        mb = wg >> 2;             // n fastest: 4 n-tiles share A rows in L2
        n0 = (wg & 3) << 8;
    } else {
        mb = blockIdx.x;
        n0 = 0;
    }
    const int m0 = mb * 128;

    if (MODE == 1) {
        if (tid < 128) preacc[tid] = 0.f;
        if (tid < 256) { b2s[tid] = b2[tid]; wls[tid] = Wl[tid]; }
        b1s[tid] = b1[tid];
    }

    // staging: A 128x32 (8 bf16/thr), B 256x32 (16 bf16/thr)
    const int sa_r = tid >> 2, sa_k = (tid & 3) << 3;
    const int sb_r = tid >> 1, sb_k = (tid & 1) << 4;
    const int gma  = m0 + sa_r;
    const bool aval = (gma < M);

    // precomputed chunk-major LDS write indices
    const int aw  = cmi(sa_r, sa_k);
    const int bw0 = cmi(sb_r, sb_k);
    const int bw1 = cmi(sb_r, sb_k + 8);

    const unsigned short* bsrc = Bt + (size_t)(n0 + sb_r) * K + sb_k;
    const unsigned short* s1 = nullptr;
    const unsigned short* s2 = nullptr;
    bool dual = false;
    if (MODE == 0) {
        if (aval) s1 = Ab + (size_t)gma * K + sa_k;
    } else if (aval) {
        if (gma < Nn) {
            s1 = out1b + (size_t)gma * H1DIM + sa_k;
        } else {
            s1 = XWb16 + (size_t)e0[gma] * NPACK + sa_k;
            s2 = XWb16 + (size_t)e1[gma] * NPACK + H1DIM + sa_k;
            dual = true;
        }
    }
    if (MODE == 1) __syncthreads();   // b1s/b2s/wls/preacc ready

    f32x4 acc[4][4];
#pragma unroll
    for (int i = 0; i < 4; ++i)
#pragma unroll
        for (int j = 0; j < 4; ++j) acc[i][j] = f32x4{0.f, 0.f, 0.f, 0.f};

    short8v ab1, ab2, bb0, bb1;

    auto load_tile = [&](int k0) {
        bb0 = *reinterpret_cast<const short8v*>(bsrc + k0);
        bb1 = *reinterpret_cast<const short8v*>(bsrc + k0 + 8);
        if (aval) {
            ab1 = *reinterpret_cast<const short8v*>(s1 + k0);
            if (MODE == 1 && dual) ab2 = *reinterpret_cast<const short8v*>(s2 + k0);
        }
    };
    auto write_lds = [&](int buf, int k0) {
        *reinterpret_cast<short8v*>(&Bs[buf][bw0]) = bb0;
        *reinterpret_cast<short8v*>(&Bs[buf][bw1]) = bb1;
        short8v av;
        if (!aval) {
            av = short8v{0,0,0,0,0,0,0,0};
        } else if (MODE == 0 || !dual) {
            av = ab1;   // bf16 passthrough (xb / out1b already converted)
        } else {
#pragma unroll
            for (int ii = 0; ii < 8; ++ii) {
                float v = bf2f((unsigned short)ab1[ii]) + bf2f((unsigned short)ab2[ii])
                        + b1s[k0 + sa_k + ii];
                v = fmaxf(v, 0.f);
                av[ii] = (short)f2bf(v);
            }
        }
        *reinterpret_cast<short8v*>(&As[buf][aw]) = av;
    };

    load_tile(0);
    int buf = 0;
    for (int k0 = 0; k0 < K; k0 += 32) {
        write_lds(buf, k0);
        __syncthreads();                     // writes to buf visible; iter i-1 reads of buf^1 done
        if (k0 + 32 < K) load_tile(k0 + 32); // reg loads overlap this step's LDS reads + MFMA

        const unsigned short* ard = &As[buf][(wm * 4) * 512 + lane * 8];
        const unsigned short* brd = &Bs[buf][(wn * 4) * 512 + lane * 8];
        short8v af[4], bfq[4];
#pragma unroll
        for (int i = 0; i < 4; ++i)
            af[i] = *reinterpret_cast<const short8v*>(ard + i * 512);
#pragma unroll
        for (int j = 0; j < 4; ++j)
            bfq[j] = *reinterpret_cast<const short8v*>(brd + j * 512);
#pragma unroll
        for (int i = 0; i < 4; ++i)
#pragma unroll
            for (int j = 0; j < 4; ++j)
                acc[i][j] = __builtin_amdgcn_mfma_f32_16x16x32_bf16(af[i], bfq[j], acc[i][j], 0, 0, 0);
        buf ^= 1;                            // next step writes other buffer: no 2nd barrier
    }

    const int crow0 = m0 + wm * 64 + ((lane >> 4) << 2);
    if (MODE == 0) {
        const int ccol = n0 + wn * 64 + (lane & 15);
#pragma unroll
        for (int i = 0; i < 4; ++i)
#pragma unroll
            for (int q = 0; q < 4; ++q) {
                const int row = crow0 + i * 16 + q;
                if (row < M) {
#pragma unroll
                    for (int j = 0; j < 4; ++j)
                        Cb[(size_t)row * NPACK + ccol + j * 16] = f2bf(acc[i][j][q]);
                }
            }
    } else {
        // fused pre = relu(h2 + b2) · Wl  (per-row scalar)
        const int cbase = wn * 64 + (lane & 15);
#pragma unroll
        for (int i = 0; i < 4; ++i)
#pragma unroll
            for (int q = 0; q < 4; ++q) {
                float v = 0.f;
#pragma unroll
                for (int j = 0; j < 4; ++j) {
                    const int c = cbase + j * 16;
                    v += fmaxf(acc[i][j][q] + b2s[c], 0.f) * wls[c];
                }
                v += __shfl_xor(v, 1, 64);
                v += __shfl_xor(v, 2, 64);
                v += __shfl_xor(v, 4, 64);
                v += __shfl_xor(v, 8, 64);
                if ((lane & 15) == 0)
                    atomicAdd(&preacc[wm * 64 + i * 16 + ((lane >> 4) << 2) + q], v);
            }
        if (m0 < Nn) {
            const int ccol = wn * 64 + (lane & 15);
#pragma unroll
            for (int i = 0; i < 4; ++i)
#pragma unroll
                for (int q = 0; q < 4; ++q) {
                    const int row = crow0 + i * 16 + q;
                    if (row < Nn) {
#pragma unroll
                        for (int j = 0; j < 4; ++j)
                            h2b[(size_t)row * H2DIM + ccol + j * 16] = f2bf(acc[i][j][q]);
                    }
                }
        }
        __syncthreads();
        // fused final (rows >= Nn): gate/mask/kld from preacc; partial -> kldp (no atomic)
        float kld = 0.f;
        if (tid < 128) {
            const int gm = m0 + tid;
            if (gm >= Nn && gm < M) {
                const float pre = preacc[tid] + blp[0];
                const float ee = eps[gm];
                const float gate = logf(ee) - log1pf(-ee) + pre;
                const float mk = 1.0f / (1.0f + expf(-gate));
                dout[1 + gm] = mk;
                kld = mk * logf(mk * 2.0f + 1e-8f)
                    + (1.0f - mk) * logf((1.0f - mk) * 2.0f + 1e-9f);
            }
        }
#pragma unroll
        for (int o = 32; o; o >>= 1) kld += __shfl_down(kld, o, 64);
        if (lane == 0) kpart[w] = kld;
        __syncthreads();
        if (tid == 0) {
            float s = 0.f;
#pragma unroll
            for (int i = 0; i < 8; ++i) s += kpart[i];
            kldp[blockIdx.x] = s;            // unconditional: no zeroing needed
        }
    }
}

// ---------------- fused: build1 (H1b) || fill (CSR srcs) ----
__global__ __launch_bounds__(256) void build1_fill_k(
    const unsigned short* __restrict__ XWb16, const float* __restrict__ dinv,
    const int* __restrict__ e0, const int* __restrict__ e1,
    unsigned short* __restrict__ H1b,
    const int* __restrict__ off, int* __restrict__ cursor, int* __restrict__ srcs,
    int N, int E)
{
    int b = blockIdx.x;
    if (b < N) {
        const int a = e0[b], c = e1[b];
        const float dv = dinv[b];
        const unsigned short* pt = XWb16 + (size_t)a * NPACK;
        const unsigned short* pb = XWb16 + (size_t)c * NPACK + H1DIM;
        const int j = threadIdx.x * 2;
        const unsigned ut = *reinterpret_cast<const unsigned*>(pt + j);
        const unsigned ub = *reinterpret_cast<const unsigned*>(pb + j);
        const float ox = (bf2f((unsigned short)(ut & 0xffff)) + bf2f((unsigned short)(ub & 0xffff))) * dv;
        const float oy = (bf2f((unsigned short)(ut >> 16))   + bf2f((unsigned short)(ub >> 16)))   * dv;
        const unsigned pk = (unsigned)f2bf(ox) | ((unsigned)f2bf(oy) << 16);
        *reinterpret_cast<unsigned*>(H1b + (size_t)b * H1DIM + j) = pk;
        return;
    }
    int e = (b - N) * 256 + threadIdx.x;
    if (e < E) {
        int t = e1[e];
        int p = off[t] + atomicAdd(&cursor[t], 1);
        srcs[p] = e0[e];
    }
}

// ---------------- CSR aggregation layer 1 -> post-relu bf16 out1 (bf16 gather, 10MB table) ----
__global__ __launch_bounds__(256) void agg1_k(
    const unsigned short* __restrict__ H1b, const int* __restrict__ off, const int* __restrict__ srcs,
    const float* __restrict__ b1, const float* __restrict__ dinv,
    unsigned short* __restrict__ out1b)
{
    const int t = blockIdx.x;
    const int j = threadIdx.x * 2;
    const int s0 = off[t], s1e = off[t + 1];
    const float dt = dinv[t];
    const unsigned u0 = *reinterpret_cast<const unsigned*>(H1b + (size_t)t * H1DIM + j);
    float ax = bf2f((unsigned short)(u0 & 0xffff));
    float ay = bf2f((unsigned short)(u0 >> 16));
    for (int i = s0; i < s1e; ++i) {
        const unsigned v = *reinterpret_cast<const unsigned*>(H1b + (size_t)srcs[i] * H1DIM + j);
        ax += bf2f((unsigned short)(v & 0xffff));
        ay += bf2f((unsigned short)(v >> 16));
    }
    const float ox = fmaxf(b1[j]     + dt * ax, 0.f);
    const float oy = fmaxf(b1[j + 1] + dt * ay, 0.f);
    const unsigned pk = (unsigned)f2bf(ox) | ((unsigned)f2bf(oy) << 16);
    *reinterpret_cast<unsigned*>(out1b + (size_t)t * H1DIM + j) = pk;
}

// ---------------- agg2 (bf16 h2) + fused final for edge t: mask -> dout[1+t], kld -> klow[t]
// (plain stores only; R13 lesson: 10k same-address atomics = 135us, plain stores free)
__global__ __launch_bounds__(128) void agg2_k(
    const unsigned short* __restrict__ h2b, const int* __restrict__ off, const int* __restrict__ srcs,
    const float* __restrict__ b2, const float* __restrict__ Wl,
    const float* __restrict__ dinv,
    const float* __restrict__ eps, const float* __restrict__ blp,
    float* __restrict__ dout, float* __restrict__ klow)
{
    __shared__ float part[2];
    const int t = blockIdx.x;
    const int j = threadIdx.x * 2;
    const int s0 = off[t], s1e = off[t + 1];
    const float dt = dinv[t];
    const unsigned u0 = *reinterpret_cast<const unsigned*>(h2b + (size_t)t * H2DIM + j);
    float ax = bf2f((unsigned short)(u0 & 0xffff)) * dt;
    float ay = bf2f((unsigned short)(u0 >> 16)) * dt;
    for (int i = s0; i < s1e; ++i) {
        const int s = srcs[i];
        const float ds = dinv[s];
        const unsigned v = *reinterpret_cast<const unsigned*>(h2b + (size_t)s * H2DIM + j);
        ax += bf2f((unsigned short)(v & 0xffff)) * ds;
        ay += bf2f((unsigned short)(v >> 16)) * ds;
    }
    float p = fmaxf(b2[j]     + dt * ax, 0.f) * Wl[j]
            + fmaxf(b2[j + 1] + dt * ay, 0.f) * Wl[j + 1];
#pragma unroll
    for (int o = 32; o; o >>= 1) p += __shfl_down(p, o, 64);
    if ((threadIdx.x & 63) == 0) part[threadIdx.x >> 6] = p;
    __syncthreads();
    if (threadIdx.x == 0) {
        const float pre = part[0] + part[1] + blp[0];
        const float ee = eps[t];
        const float gate = logf(ee) - log1pf(-ee) + pre;
        const float mk = 1.0f / (1.0f + expf(-gate));
        dout[1 + t] = mk;
        klow[t] = mk * logf(mk * 2.0f + 1e-8f)
                + (1.0f - mk) * logf((1.0f - mk) * 2.0f + 1e-9f);
    }
}

// ---------------- reduce: dout[0] = (sum kldp + sum klow) / E  (single block, plain store) ----
__global__ __launch_bounds__(256) void reduce_k(
    const float* __restrict__ kldp, int npart,
    const float* __restrict__ klow, int Nn,
    float* __restrict__ dout, int Etot)
{
    __shared__ float part[4];
    float s = 0.f;
    for (int i = threadIdx.x; i < npart; i += 256) s += kldp[i];
    for (int i = threadIdx.x; i < Nn; i += 256) s += klow[i];
#pragma unroll
    for (int o = 32; o; o >>= 1) s += __shfl_down(s, o, 64);
    const int lane = threadIdx.x & 63, wv = threadIdx.x >> 6;
    if (lane == 0) part[wv] = s;
    __syncthreads();
    if (threadIdx.x == 0)
        dout[0] = (part[0] + part[1] + part[2] + part[3]) / (float)Etot;
}

// ---------------- host ----------------
extern "C" void kernel_launch(void* const* d_in, const int* in_sizes, int n_in,
                              void* d_out, int out_size, void* d_ws, size_t ws_size,
                              hipStream_t stream)
{
    const float* x   = (const float*)d_in[0];
    const int*   ei  = (const int*)d_in[1];
    const float* eps = (const float*)d_in[2];
    const float* W1  = (const float*)d_in[3];
    const float* b1  = (const float*)d_in[4];
    const float* W2  = (const float*)d_in[5];
    const float* b2  = (const float*)d_in[6];
    const float* Wl  = (const float*)d_in[7];
    const float* bl  = (const float*)d_in[8];
    float* out = (float*)d_out;
    float* ws  = (float*)d_ws;

    const int N = in_sizes[0] / DNODE;   // 10000
    const int E = in_sizes[1] / 2;       // 100000
    const int* e0 = ei;
    const int* e1 = ei + E;
    const int nwg2 = (E + 127) / 128;    // GEMM2 tile count (= kld partial count)

    // workspace layout
    float* dinv     = ws;                                        // 16384
    float* klow     = dinv + 16384;                              // N (pad 16384)
    float* kldp     = klow + 16384;                              // nwg2 (pad 1024)
    float* fend     = kldp + 1024;
    unsigned short* XWb16 = (unsigned short*)fend;               // N*1024 bf16
    unsigned short* out1b = XWb16 + (size_t)N * NPACK;           // N*512 bf16
    unsigned short* H1b   = out1b + (size_t)N * H1DIM;           // N*512 bf16
    unsigned short* h2b   = H1b + (size_t)N * H1DIM;             // N*256 bf16
    unsigned short* xb    = h2b + (size_t)N * H2DIM;             // N*1280 bf16
    unsigned short* Bpt1  = xb + (size_t)N * DNODE;              // 1024*1280 bf16
    unsigned short* W2t   = Bpt1 + (size_t)NPACK * DNODE;        // 256*512 bf16
    int* hist   = (int*)(W2t + (size_t)H2DIM * H1DIM);           // N
    int* cursor = hist + N;                                      // N
    int* off    = cursor + N;                                    // N+1
    int* srcs   = off + (N + 1);                                 // E

    // 0) async zero: hist (kld accumulator now single-writer plain store, no zero needed)
    (void)hipMemsetAsync(hist, 0, (size_t)N * sizeof(int), stream);

    // 1) fused prep: cvt_x || hist || W1/W2 transposes
    {
        const int ntot = N * DNODE;
        const int ncvt = (ntot / 4 + 255) / 256;
        const int nhist = (E + 255) / 256;
        const int ntr = 640 + 640 + 128;
        prep_k<<<ncvt + nhist + ntr, 256, 0, stream>>>(
            x, xb, ncvt, ntot, e1, hist, nhist, E, W1, Bpt1, W2, W2t);
    }

    // 2) GEMM1 || CSR-scan: XWb16 = xb @ [W1top|W1bot]; scan hidden in block nwg
    {
        const int nwg = 4 * ((N + 127) / 128);
        gemm_u_k<0><<<nwg + 1, 512, 0, stream>>>(
            xb, Bpt1, XWb16, nullptr, nullptr, b1, b2, Wl, e0, e1,
            off, nullptr, nullptr, hist, cursor, dinv,
            nullptr, nullptr, nullptr, nullptr, N, DNODE, N, nwg);
    }

    // 3) build1 (H1b messages) || fill (CSR srcs)
    build1_fill_k<<<N + (E + 255) / 256, 256, 0, stream>>>(
        XWb16, dinv, e0, e1, H1b, off, cursor, srcs, N, E);

    // 4) layer-1 CSR aggregation (post-relu bf16 out1)
    agg1_k<<<N, 256, 0, stream>>>(H1b, off, srcs, b1, dinv, out1b);

    // 5) GEMM2: h2 rows<N (bf16) + fused final rows >= N (mask; kld partial -> kldp)
    gemm_u_k<1><<<nwg2, 512, 0, stream>>>(
        nullptr, W2t, nullptr, out1b, XWb16, b1, b2, Wl, e0, e1,
        off, srcs, h2b, nullptr, nullptr, dinv,
        eps, bl, out, kldp, E, H1DIM, N, nwg2);

    // 6) agg2 + fused final for edges t < N (mask + klow partial, plain stores)
    agg2_k<<<N, 128, 0, stream>>>(h2b, off, srcs, b2, Wl, dinv, eps, bl, out, klow);

    // 7) reduce kld partials -> dout[0] (single block, zero atomics)
    reduce_k<<<1, 256, 0, stream>>>(kldp, nwg2, klow, N, out, E);
}

// Round 17
// 191.161 us; speedup vs baseline: 1.0435x; 1.0435x over previous
//
#include <hip/hip_runtime.h>
#include <cstdint>
#include <cstddef>

#define H1DIM 512
#define H2DIM 256
#define DNODE 1280
#define NPACK 1024   // GEMM1 packed output width (XWt | XWb), bf16

typedef __attribute__((ext_vector_type(8))) short short8v;
typedef __attribute__((ext_vector_type(4))) float f32x4;
typedef __attribute__((ext_vector_type(4))) unsigned short us4;

__device__ __forceinline__ unsigned short f2bf(float f) {
    unsigned int u = __builtin_bit_cast(unsigned int, f);
    u += 0x7fffu + ((u >> 16) & 1u);   // RNE
    return (unsigned short)(u >> 16);
}
__device__ __forceinline__ float bf2f(unsigned short h) {
    unsigned int u = ((unsigned int)h) << 16;
    return __builtin_bit_cast(float, u);
}

// chunk-major LDS index (2-way/zero bank conflicts, proven R6-R10):
// tile row R, k-chunk q (8 ushorts) -> segment R>>4, slot q*16 + (R&15),
// ushort index = (R>>4)*512 + slot*8. Fragment read: seg*512 + lane*8.
__device__ __forceinline__ int cmi(int R, int kq) {
    return ((R >> 4) << 9) + (((kq >> 3) << 4) + (R & 15)) * 8;
}

// ---------------- fused prep: cvt_x || hist || 3 weight transposes (block-range dispatch) ----
// R12 lesson: block-range fusion only between regions of matching small footprint.
__global__ __launch_bounds__(256) void prep_k(
    const float* __restrict__ x, unsigned short* __restrict__ xb, int ncvt, int ntot,
    const int* __restrict__ e1, int* __restrict__ hist, int nhist, int E,
    const float* __restrict__ W1, unsigned short* __restrict__ Bpt1,
    const float* __restrict__ W2, unsigned short* __restrict__ W2t)
{
    __shared__ float tile[32][33];
    int b = blockIdx.x;

    if (b < ncvt) {                       // region 1: x fp32 -> bf16 (f32x4/thread)
        int i = b * 256 + threadIdx.x;
        if (i * 4 < ntot) {
            f32x4 v = *reinterpret_cast<const f32x4*>(x + (size_t)i * 4);
            us4 o;
            o[0] = f2bf(v.x); o[1] = f2bf(v.y); o[2] = f2bf(v.z); o[3] = f2bf(v.w);
            *reinterpret_cast<us4*>(xb + (size_t)i * 4) = o;
        }
        return;
    }
    b -= ncvt;
    if (b < nhist) {                      // region 2: degree histogram
        int e = b * 256 + threadIdx.x;
        if (e < E) atomicAdd(&hist[e1[e]], 1);
        return;
    }
    b -= nhist;

    // region 3: transpose+cvt (W1 top | W1 bottom | W2), block-uniform branch
    const float* src; unsigned short* dst; int ldsrc, lddst, bx, by;
    if (b < 640) {                        // W1 top: [1280][512] -> Bpt1 [512][1280]
        src = W1; dst = Bpt1; ldsrc = H1DIM; lddst = DNODE; bx = b & 15; by = b >> 4;
    } else if (b < 1280) {                // W1 bottom
        b -= 640;
        src = W1 + (size_t)DNODE * H1DIM; dst = Bpt1 + (size_t)H1DIM * DNODE;
        ldsrc = H1DIM; lddst = DNODE; bx = b & 15; by = b >> 4;
    } else {                              // W2: [512][256] -> W2t [256][512]
        b -= 1280;
        src = W2; dst = W2t; ldsrc = H2DIM; lddst = H1DIM; bx = b & 7; by = b >> 3;
    }
    const int c0 = bx * 32, r0 = by * 32;
    const int tx = threadIdx.x & 31;
    const int ty = threadIdx.x >> 5;
#pragma unroll
    for (int rr = ty; rr < 32; rr += 8)
        tile[rr][tx] = src[(size_t)(r0 + rr) * ldsrc + c0 + tx];
    __syncthreads();
#pragma unroll
    for (int rr = ty; rr < 32; rr += 8)
        dst[(size_t)(c0 + rr) * lddst + r0 + tx] = f2bf(tile[tx][rr]);
}

// ---------------- unified bf16 MFMA GEMM, tile 128x256, BK=32, 512 thr (8 waves 2Mx4N) ----
// R8 schedule: reg-staged loads, double-buffered chunk-major LDS, ONE barrier per K-step.
// MODE 0: blocks [0,nwg) GEMM1 tiles (XCD swizzle); block nwg runs the CSR scan (hidden).
// MODE 1: GEMM2. Epilogue fuses final gumbel-sigmoid for rows >= Nn; kld partial goes to
//   kldp[blockIdx] (NON-atomic; R14 lesson: ~700 same-address atomics in cohort-retiring
//   GEMM blocks serialize ~6us). final_low_k sums the partials with ONE atomic.
template <int MODE>
__global__ __launch_bounds__(512) void gemm_u_k(
    const unsigned short* __restrict__ Ab,
    const unsigned short* __restrict__ Bt,
    unsigned short* __restrict__ Cb,
    const unsigned short* __restrict__ out1b,
    const unsigned short* __restrict__ XWb16,
    const float* __restrict__ b1,
    const float* __restrict__ b2,
    const float* __restrict__ Wl,
    const int* __restrict__ e0, const int* __restrict__ e1,
    int* __restrict__ off, const int* __restrict__ srcs,
    unsigned short* __restrict__ h2b,
    int* __restrict__ hist, int* __restrict__ cursor, float* __restrict__ dinv,
    const float* __restrict__ eps, const float* __restrict__ blp, float* __restrict__ dout,
    float* __restrict__ kldp,
    int M, int K, int Nn, int nwg)
{
    const int tid  = threadIdx.x;

    if (MODE == 0 && blockIdx.x >= (unsigned)nwg) {
        // ---- CSR scan + dinv (512-thread variant), 1 block, hidden under GEMM1 ----
        __shared__ int part[512];
        const int t = tid;
        const int per = (Nn + 511) / 512;
        const int base = t * per;
        int s = 0;
        for (int i = 0; i < per; ++i) { int b = base + i; if (b < Nn) s += hist[b]; }
        part[t] = s;
        __syncthreads();
        for (int d = 1; d < 512; d <<= 1) {
            int v = (t >= d) ? part[t - d] : 0;
            __syncthreads();
            part[t] += v;
            __syncthreads();
        }
        int run = (t == 0) ? 0 : part[t - 1];
        for (int i = 0; i < per; ++i) {
            int b = base + i;
            if (b < Nn) {
                int h = hist[b];
                off[b] = run;
                run += h;
                cursor[b] = 0;
                dinv[b] = rsqrtf(1.0f + (float)h);
            }
        }
        if (t == 511) off[Nn] = run;
        return;
    }

    __shared__ alignas(16) unsigned short As[2][128 * 32];
    __shared__ alignas(16) unsigned short Bs[2][256 * 32];
    __shared__ float b1s[H1DIM];
    __shared__ float b2s[H2DIM];
    __shared__ float wls[H2DIM];
    __shared__ float preacc[128];
    __shared__ float kpart[8];

    const int lane = tid & 63;
    const int w    = tid >> 6;
    const int wm   = w >> 2, wn = w & 3;

    int mb, n0;
    if (MODE == 0) {
        // bijective XCD swizzle (m204): consecutive logical tiles land on one XCD
        const int q = nwg >> 3, r = nwg & 7;
        const int xcd = blockIdx.x & 7;
        const int base = (xcd < r) ? xcd * (q + 1) : r * (q + 1) + (xcd - r) * q;
        const int wg = base + (blockIdx.x >> 3);
        mb = wg >> 2;             // n fastest: 4 n-tiles share A rows in L2
        n0 = (wg & 3) << 8;
    } else {
        mb = blockIdx.x;
        n0 = 0;
    }
    const int m0 = mb * 128;

    if (MODE == 1) {
        if (tid < 128) preacc[tid] = 0.f;
        if (tid < 256) { b2s[tid] = b2[tid]; wls[tid] = Wl[tid]; }
        b1s[tid] = b1[tid];
    }

    // staging: A 128x32 (8 bf16/thr), B 256x32 (16 bf16/thr)
    const int sa_r = tid >> 2, sa_k = (tid & 3) << 3;
    const int sb_r = tid >> 1, sb_k = (tid & 1) << 4;
    const int gma  = m0 + sa_r;
    const bool aval = (gma < M);

    // precomputed chunk-major LDS write indices
    const int aw  = cmi(sa_r, sa_k);
    const int bw0 = cmi(sb_r, sb_k);
    const int bw1 = cmi(sb_r, sb_k + 8);

    const unsigned short* bsrc = Bt + (size_t)(n0 + sb_r) * K + sb_k;
    const unsigned short* s1 = nullptr;
    const unsigned short* s2 = nullptr;
    bool dual = false;
    if (MODE == 0) {
        if (aval) s1 = Ab + (size_t)gma * K + sa_k;
    } else if (aval) {
        if (gma < Nn) {
            s1 = out1b + (size_t)gma * H1DIM + sa_k;
        } else {
            s1 = XWb16 + (size_t)e0[gma] * NPACK + sa_k;
            s2 = XWb16 + (size_t)e1[gma] * NPACK + H1DIM + sa_k;
            dual = true;
        }
    }
    if (MODE == 1) __syncthreads();   // b1s/b2s/wls/preacc ready

    f32x4 acc[4][4];
#pragma unroll
    for (int i = 0; i < 4; ++i)
#pragma unroll
        for (int j = 0; j < 4; ++j) acc[i][j] = f32x4{0.f, 0.f, 0.f, 0.f};

    short8v ab1, ab2, bb0, bb1;

    auto load_tile = [&](int k0) {
        bb0 = *reinterpret_cast<const short8v*>(bsrc + k0);
        bb1 = *reinterpret_cast<const short8v*>(bsrc + k0 + 8);
        if (aval) {
            ab1 = *reinterpret_cast<const short8v*>(s1 + k0);
            if (MODE == 1 && dual) ab2 = *reinterpret_cast<const short8v*>(s2 + k0);
        }
    };
    auto write_lds = [&](int buf, int k0) {
        *reinterpret_cast<short8v*>(&Bs[buf][bw0]) = bb0;
        *reinterpret_cast<short8v*>(&Bs[buf][bw1]) = bb1;
        short8v av;
        if (!aval) {
            av = short8v{0,0,0,0,0,0,0,0};
        } else if (MODE == 0 || !dual) {
            av = ab1;   // bf16 passthrough (xb / out1b already converted)
        } else {
#pragma unroll
            for (int ii = 0; ii < 8; ++ii) {
                float v = bf2f((unsigned short)ab1[ii]) + bf2f((unsigned short)ab2[ii])
                        + b1s[k0 + sa_k + ii];
                v = fmaxf(v, 0.f);
                av[ii] = (short)f2bf(v);
            }
        }
        *reinterpret_cast<short8v*>(&As[buf][aw]) = av;
    };

    load_tile(0);
    int buf = 0;
    for (int k0 = 0; k0 < K; k0 += 32) {
        write_lds(buf, k0);
        __syncthreads();                     // writes to buf visible; iter i-1 reads of buf^1 done
        if (k0 + 32 < K) load_tile(k0 + 32); // reg loads overlap this step's LDS reads + MFMA

        const unsigned short* ard = &As[buf][(wm * 4) * 512 + lane * 8];
        const unsigned short* brd = &Bs[buf][(wn * 4) * 512 + lane * 8];
        short8v af[4], bfq[4];
#pragma unroll
        for (int i = 0; i < 4; ++i)
            af[i] = *reinterpret_cast<const short8v*>(ard + i * 512);
#pragma unroll
        for (int j = 0; j < 4; ++j)
            bfq[j] = *reinterpret_cast<const short8v*>(brd + j * 512);
#pragma unroll
        for (int i = 0; i < 4; ++i)
#pragma unroll
            for (int j = 0; j < 4; ++j)
                acc[i][j] = __builtin_amdgcn_mfma_f32_16x16x32_bf16(af[i], bfq[j], acc[i][j], 0, 0, 0);
        buf ^= 1;                            // next step writes other buffer: no 2nd barrier
    }

    const int crow0 = m0 + wm * 64 + ((lane >> 4) << 2);
    if (MODE == 0) {
        const int ccol = n0 + wn * 64 + (lane & 15);
#pragma unroll
        for (int i = 0; i < 4; ++i)
#pragma unroll
            for (int q = 0; q < 4; ++q) {
                const int row = crow0 + i * 16 + q;
                if (row < M) {
#pragma unroll
                    for (int j = 0; j < 4; ++j)
                        Cb[(size_t)row * NPACK + ccol + j * 16] = f2bf(acc[i][j][q]);
                }
            }
    } else {
        // fused pre = relu(h2 + b2) · Wl  (per-row scalar)
        const int cbase = wn * 64 + (lane & 15);
#pragma unroll
        for (int i = 0; i < 4; ++i)
#pragma unroll
            for (int q = 0; q < 4; ++q) {
                float v = 0.f;
#pragma unroll
                for (int j = 0; j < 4; ++j) {
                    const int c = cbase + j * 16;
                    v += fmaxf(acc[i][j][q] + b2s[c], 0.f) * wls[c];
                }
                v += __shfl_xor(v, 1, 64);
                v += __shfl_xor(v, 2, 64);
                v += __shfl_xor(v, 4, 64);
                v += __shfl_xor(v, 8, 64);
                if ((lane & 15) == 0)
                    atomicAdd(&preacc[wm * 64 + i * 16 + ((lane >> 4) << 2) + q], v);
            }
        if (m0 < Nn) {
            const int ccol = wn * 64 + (lane & 15);
#pragma unroll
            for (int i = 0; i < 4; ++i)
#pragma unroll
                for (int q = 0; q < 4; ++q) {
                    const int row = crow0 + i * 16 + q;
                    if (row < Nn) {
#pragma unroll
                        for (int j = 0; j < 4; ++j)
                            h2b[(size_t)row * H2DIM + ccol + j * 16] = f2bf(acc[i][j][q]);
                    }
                }
        }
        __syncthreads();
        // fused final (rows >= Nn): gate/mask/kld from preacc; partial -> kldp (no atomic)
        float kld = 0.f;
        if (tid < 128) {
            const int gm = m0 + tid;
            if (gm >= Nn && gm < M) {
                const float pre = preacc[tid] + blp[0];
                const float ee = eps[gm];
                const float gate = logf(ee) - log1pf(-ee) + pre;
                const float mk = 1.0f / (1.0f + expf(-gate));
                dout[1 + gm] = mk;
                kld = mk * logf(mk * 2.0f + 1e-8f)
                    + (1.0f - mk) * logf((1.0f - mk) * 2.0f + 1e-9f);
            }
        }
#pragma unroll
        for (int o = 32; o; o >>= 1) kld += __shfl_down(kld, o, 64);
        if (lane == 0) kpart[w] = kld;
        __syncthreads();
        if (tid == 0) {
            float s = 0.f;
#pragma unroll
            for (int i = 0; i < 8; ++i) s += kpart[i];
            kldp[blockIdx.x] = s;            // unconditional: no zeroing needed
        }
    }
}

// ---------------- fused: build1 (H1b) || fill (CSR srcs) ----
__global__ __launch_bounds__(256) void build1_fill_k(
    const unsigned short* __restrict__ XWb16, const float* __restrict__ dinv,
    const int* __restrict__ e0, const int* __restrict__ e1,
    unsigned short* __restrict__ H1b,
    const int* __restrict__ off, int* __restrict__ cursor, int* __restrict__ srcs,
    int N, int E)
{
    int b = blockIdx.x;
    if (b < N) {
        const int a = e0[b], c = e1[b];
        const float dv = dinv[b];
        const unsigned short* pt = XWb16 + (size_t)a * NPACK;
        const unsigned short* pb = XWb16 + (size_t)c * NPACK + H1DIM;
        const int j = threadIdx.x * 2;
        const unsigned ut = *reinterpret_cast<const unsigned*>(pt + j);
        const unsigned ub = *reinterpret_cast<const unsigned*>(pb + j);
        const float ox = (bf2f((unsigned short)(ut & 0xffff)) + bf2f((unsigned short)(ub & 0xffff))) * dv;
        const float oy = (bf2f((unsigned short)(ut >> 16))   + bf2f((unsigned short)(ub >> 16)))   * dv;
        const unsigned pk = (unsigned)f2bf(ox) | ((unsigned)f2bf(oy) << 16);
        *reinterpret_cast<unsigned*>(H1b + (size_t)b * H1DIM + j) = pk;
        return;
    }
    int e = (b - N) * 256 + threadIdx.x;
    if (e < E) {
        int t = e1[e];
        int p = off[t] + atomicAdd(&cursor[t], 1);
        srcs[p] = e0[e];
    }
}

// ---------------- CSR aggregation layer 1 -> post-relu bf16 out1 (bf16 gather, 10MB table) ----
__global__ __launch_bounds__(256) void agg1_k(
    const unsigned short* __restrict__ H1b, const int* __restrict__ off, const int* __restrict__ srcs,
    const float* __restrict__ b1, const float* __restrict__ dinv,
    unsigned short* __restrict__ out1b)
{
    const int t = blockIdx.x;
    const int j = threadIdx.x * 2;
    const int s0 = off[t], s1e = off[t + 1];
    const float dt = dinv[t];
    const unsigned u0 = *reinterpret_cast<const unsigned*>(H1b + (size_t)t * H1DIM + j);
    float ax = bf2f((unsigned short)(u0 & 0xffff));
    float ay = bf2f((unsigned short)(u0 >> 16));
    for (int i = s0; i < s1e; ++i) {
        const unsigned v = *reinterpret_cast<const unsigned*>(H1b + (size_t)srcs[i] * H1DIM + j);
        ax += bf2f((unsigned short)(v & 0xffff));
        ay += bf2f((unsigned short)(v >> 16));
    }
    const float ox = fmaxf(b1[j]     + dt * ax, 0.f);
    const float oy = fmaxf(b1[j + 1] + dt * ay, 0.f);
    const unsigned pk = (unsigned)f2bf(ox) | ((unsigned)f2bf(oy) << 16);
    *reinterpret_cast<unsigned*>(out1b + (size_t)t * H1DIM + j) = pk;
}

// ---------------- agg2 (bf16 h2) fused with Wl dot -> pre_low[t] (NO atomics) ----
__global__ __launch_bounds__(128) void agg2_k(
    const unsigned short* __restrict__ h2b, const int* __restrict__ off, const int* __restrict__ srcs,
    const float* __restrict__ b2, const float* __restrict__ Wl,
    const float* __restrict__ dinv, float* __restrict__ pre_low)
{
    __shared__ float part[2];
    const int t = blockIdx.x;
    const int j = threadIdx.x * 2;
    const int s0 = off[t], s1e = off[t + 1];
    const float dt = dinv[t];
    const unsigned u0 = *reinterpret_cast<const unsigned*>(h2b + (size_t)t * H2DIM + j);
    float ax = bf2f((unsigned short)(u0 & 0xffff)) * dt;
    float ay = bf2f((unsigned short)(u0 >> 16)) * dt;
    for (int i = s0; i < s1e; ++i) {
        const int s = srcs[i];
        const float ds = dinv[s];
        const unsigned v = *reinterpret_cast<const unsigned*>(h2b + (size_t)s * H2DIM + j);
        ax += bf2f((unsigned short)(v & 0xffff)) * ds;
        ay += bf2f((unsigned short)(v >> 16)) * ds;
    }
    float p = fmaxf(b2[j]     + dt * ax, 0.f) * Wl[j]
            + fmaxf(b2[j + 1] + dt * ay, 0.f) * Wl[j + 1];
#pragma unroll
    for (int o = 32; o; o >>= 1) p += __shfl_down(p, o, 64);
    if ((threadIdx.x & 63) == 0) part[threadIdx.x >> 6] = p;
    __syncthreads();
    if (threadIdx.x == 0) pre_low[t] = part[0] + part[1];
}

// ---------------- final: low edges (t < N) mask+kld, + 1 block reduces GEMM2 kld partials ----
__global__ __launch_bounds__(256) void final_low_k(
    const float* __restrict__ pre_low, const float* __restrict__ blp,
    const float* __restrict__ eps, float* __restrict__ dout,
    const float* __restrict__ kldp, int npart, int Nn, int Etot)
{
    __shared__ float part[4];
    if (blockIdx.x == gridDim.x - 1) {
        // reduce GEMM2's per-block kld partials (one atomic total)
        float s = 0.f;
        for (int i = threadIdx.x; i < npart; i += 256) s += kldp[i];
#pragma unroll
        for (int o = 32; o; o >>= 1) s += __shfl_down(s, o, 64);
        const int lane = threadIdx.x & 63, wv = threadIdx.x >> 6;
        if (lane == 0) part[wv] = s;
        __syncthreads();
        if (threadIdx.x == 0)
            atomicAdd(&dout[0], (part[0] + part[1] + part[2] + part[3]) / (float)Etot);
        return;
    }
    const int i = blockIdx.x * 256 + threadIdx.x;
    float kld = 0.f;
    if (i < Nn) {
        const float pre = pre_low[i] + blp[0];
        const float ee = eps[i];
        const float gate = logf(ee) - log1pf(-ee) + pre;
        const float m = 1.0f / (1.0f + expf(-gate));
        dout[1 + i] = m;
        kld = m * logf(m * 2.0f + 1e-8f)
            + (1.0f - m) * logf((1.0f - m) * 2.0f + 1e-9f);
    }
#pragma unroll
    for (int o = 32; o; o >>= 1) kld += __shfl_down(kld, o, 64);
    const int lane = threadIdx.x & 63, wv = threadIdx.x >> 6;
    if (lane == 0) part[wv] = kld;
    __syncthreads();
    if (threadIdx.x == 0)
        atomicAdd(&dout[0], (part[0] + part[1] + part[2] + part[3]) / (float)Etot);
}

// ---------------- host ----------------
extern "C" void kernel_launch(void* const* d_in, const int* in_sizes, int n_in,
                              void* d_out, int out_size, void* d_ws, size_t ws_size,
                              hipStream_t stream)
{
    const float* x   = (const float*)d_in[0];
    const int*   ei  = (const int*)d_in[1];
    const float* eps = (const float*)d_in[2];
    const float* W1  = (const float*)d_in[3];
    const float* b1  = (const float*)d_in[4];
    const float* W2  = (const float*)d_in[5];
    const float* b2  = (const float*)d_in[6];
    const float* Wl  = (const float*)d_in[7];
    const float* bl  = (const float*)d_in[8];
    float* out = (float*)d_out;
    float* ws  = (float*)d_ws;

    const int N = in_sizes[0] / DNODE;   // 10000
    const int E = in_sizes[1] / 2;       // 100000
    const int* e0 = ei;
    const int* e1 = ei + E;
    const int nwg2 = (E + 127) / 128;    // GEMM2 tile count (= kld partial count)

    // workspace layout
    float* dinv     = ws;                                        // 16384
    float* pre_low  = dinv + 16384;                              // N (pad 16384)
    float* kldp     = pre_low + 16384;                           // nwg2 (pad 1024)
    float* fend     = kldp + 1024;
    unsigned short* XWb16 = (unsigned short*)fend;               // N*1024 bf16
    unsigned short* out1b = XWb16 + (size_t)N * NPACK;           // N*512 bf16
    unsigned short* H1b   = out1b + (size_t)N * H1DIM;           // N*512 bf16
    unsigned short* h2b   = H1b + (size_t)N * H1DIM;             // N*256 bf16
    unsigned short* xb    = h2b + (size_t)N * H2DIM;             // N*1280 bf16
    unsigned short* Bpt1  = xb + (size_t)N * DNODE;              // 1024*1280 bf16
    unsigned short* W2t   = Bpt1 + (size_t)NPACK * DNODE;        // 256*512 bf16
    int* hist   = (int*)(W2t + (size_t)H2DIM * H1DIM);           // N
    int* cursor = hist + N;                                      // N
    int* off    = cursor + N;                                    // N+1
    int* srcs   = off + (N + 1);                                 // E

    // 0) async zero: hist and kld accumulator
    (void)hipMemsetAsync(hist, 0, (size_t)N * sizeof(int), stream);
    (void)hipMemsetAsync(out, 0, sizeof(float), stream);

    // 1) fused prep: cvt_x || hist || W1/W2 transposes
    {
        const int ntot = N * DNODE;
        const int ncvt = (ntot / 4 + 255) / 256;
        const int nhist = (E + 255) / 256;
        const int ntr = 640 + 640 + 128;
        prep_k<<<ncvt + nhist + ntr, 256, 0, stream>>>(
            x, xb, ncvt, ntot, e1, hist, nhist, E, W1, Bpt1, W2, W2t);
    }

    // 2) GEMM1 || CSR-scan: XWb16 = xb @ [W1top|W1bot]; scan hidden in block nwg
    {
        const int nwg = 4 * ((N + 127) / 128);
        gemm_u_k<0><<<nwg + 1, 512, 0, stream>>>(
            xb, Bpt1, XWb16, nullptr, nullptr, b1, b2, Wl, e0, e1,
            off, nullptr, nullptr, hist, cursor, dinv,
            nullptr, nullptr, nullptr, nullptr, N, DNODE, N, nwg);
    }

    // 3) build1 (H1b messages) || fill (CSR srcs)
    build1_fill_k<<<N + (E + 255) / 256, 256, 0, stream>>>(
        XWb16, dinv, e0, e1, H1b, off, cursor, srcs, N, E);

    // 4) layer-1 CSR aggregation (post-relu bf16 out1)
    agg1_k<<<N, 256, 0, stream>>>(H1b, off, srcs, b1, dinv, out1b);

    // 5) GEMM2: h2 rows<N (bf16) + fused final rows >= N (mask; kld partial -> kldp, no atomic)
    gemm_u_k<1><<<nwg2, 512, 0, stream>>>(
        nullptr, W2t, nullptr, out1b, XWb16, b1, b2, Wl, e0, e1,
        off, srcs, h2b, nullptr, nullptr, dinv,
        eps, bl, out, kldp, E, H1DIM, N, nwg2);

    // 6) agg2 -> pre_low (no atomics)
    agg2_k<<<N, 128, 0, stream>>>(h2b, off, srcs, b2, Wl, dinv, pre_low);

    // 7) final: low edges + kld-partial reduction (41 atomics total)
    final_low_k<<<(N + 255) / 256 + 1, 256, 0, stream>>>(
        pre_low, bl, eps, out, kldp, nwg2, N, E);
}